// Round 6
// baseline (362.005 us; speedup 1.0000x reference)
//
#include <hip/hip_runtime.h>
#include <hip/hip_bf16.h>

#define EPS_Z 1e-4f

typedef __attribute__((ext_vector_type(8))) short bf16x8;
typedef __attribute__((ext_vector_type(4))) float f32x4;

__device__ __forceinline__ float b2f(short s) {
    union { unsigned u; float f; } cv;
    cv.u = ((unsigned)(unsigned short)s) << 16;
    return cv.f;
}

__device__ __forceinline__ void gld_lds16(const __hip_bfloat16* g, __hip_bfloat16* l) {
    __builtin_amdgcn_global_load_lds(
        (__attribute__((address_space(1))) void*)(g),
        (__attribute__((address_space(3))) void*)(l),
        16, 0, 0);
}

// fp32 -> bf16 (RNE), 4 elems/thread
__global__ __launch_bounds__(256)
void cvt_f32_bf16(const float* __restrict__ in, __hip_bfloat16* __restrict__ out, int n4)
{
    int i = blockIdx.x * 256 + threadIdx.x;
    if (i >= n4) return;
    float4 v = ((const float4*)in)[i];
    union { short4 s; __hip_bfloat16 h[4]; } o;
    o.h[0] = __float2bfloat16(v.x);
    o.h[1] = __float2bfloat16(v.y);
    o.h[2] = __float2bfloat16(v.z);
    o.h[3] = __float2bfloat16(v.w);
    ((short4*)out)[i] = o.s;
}

// C[M,N] = A[M,K] @ B[N,K]^T ; A,B bf16, fp32 accumulate. (validated R4 structure)
template<int MODE, typename CT>
__global__ __launch_bounds__(256, 2)
void gemm_bt(const __hip_bfloat16* __restrict__ A,
             const __hip_bfloat16* __restrict__ B,
             CT* __restrict__ C,
             const float* __restrict__ bias,
             int K, int N, int gx)
{
    __shared__ __align__(16) __hip_bfloat16 As[128 * 64];
    __shared__ __align__(16) __hip_bfloat16 Bs[128 * 64];
    const int g = blockIdx.x;
    const int gp = (g & 7) * ((int)gridDim.x >> 3) + (g >> 3);
    const int bx = gp % gx;
    const int by = gp / gx;

    const int tid = threadIdx.x;
    const int w = tid >> 6;
    const int l = tid & 63;
    const int wr = (w >> 1) * 64;
    const int wc = (w & 1) * 64;
    const int l15 = l & 15;
    const int lq = l >> 4;
    const int rx = l15 & 7;

    f32x4 acc[4][4] = {};

    const int srow8 = l >> 3;
    const int scol = (((l & 7) ^ (l >> 3)) << 3);

    const __hip_bfloat16* Ab = A + (size_t)by * 128 * K;
    const __hip_bfloat16* Bb = B + (size_t)bx * 128 * K;

    for (int k0 = 0; k0 < K; k0 += 64) {
        __syncthreads();
        #pragma unroll
        for (int i = 0; i < 4; ++i) {
            const int chunk = w * 4 + i;
            const int row = chunk * 8 + srow8;
            gld_lds16(Ab + (size_t)row * K + (k0 + scol), As + chunk * 512);
            gld_lds16(Bb + (size_t)row * K + (k0 + scol), Bs + chunk * 512);
        }
        __syncthreads();
        #pragma unroll
        for (int kk = 0; kk < 64; kk += 32) {
            const int kb = (kk >> 3) + lq;
            const int col = (kb ^ rx) << 3;
            bf16x8 a[4], b[4];
            #pragma unroll
            for (int i = 0; i < 4; ++i)
                a[i] = *(const bf16x8*)(As + (wr + i * 16 + l15) * 64 + col);
            #pragma unroll
            for (int j = 0; j < 4; ++j)
                b[j] = *(const bf16x8*)(Bs + (wc + j * 16 + l15) * 64 + col);
            #pragma unroll
            for (int i = 0; i < 4; ++i)
                #pragma unroll
                for (int j = 0; j < 4; ++j)
                    acc[i][j] = __builtin_amdgcn_mfma_f32_16x16x32_bf16(a[i], b[j], acc[i][j], 0, 0, 0);
        }
    }

    const int crow0 = by * 128 + wr + lq * 4;
    const int ccol0 = bx * 128 + wc + l15;
    #pragma unroll
    for (int i = 0; i < 4; ++i) {
        #pragma unroll
        for (int j = 0; j < 4; ++j) {
            const int gc = ccol0 + j * 16;
            const float badd = (MODE == 2) ? bias[gc] : 0.0f;
            #pragma unroll
            for (int r = 0; r < 4; ++r) {
                const int gr = crow0 + i * 16 + r;
                float v = acc[i][j][r];
                if (MODE == 1 && gc < 1536) v = fmaxf(v, 0.0f);
                if (MODE == 2) v += badd;
                if (MODE == 1)
                    ((__hip_bfloat16*)C)[(size_t)gr * N + gc] = __float2bfloat16(v);
                else
                    ((float*)C)[(size_t)gr * N + gc] = v;
            }
        }
    }
}

// kv^T[bh][d][e] = sum_s v[s,d]*k[s,e]  (fp32 atomics, split-S x14)
// Ping-pong double-buffered LDS transpose: ONE barrier per 32-s chunk; next
// chunk's global loads issue right after the barrier and fly during the MFMAs.
__global__ __launch_bounds__(256)
void kv_mfma_kernel(const __hip_bfloat16* __restrict__ qkv,
                    float* __restrict__ kvg, float* __restrict__ ksumg)
{
    const int SPLIT = 14;
    const int bh = blockIdx.x / SPLIT;
    const int ck = blockIdx.x % SPLIT;
    const int b = bh / 12, h = bh % 12;

    __shared__ __align__(16) __hip_bfloat16 kT[2][64 * 40];   // [buf][e][s32], stride 40
    __shared__ __align__(16) __hip_bfloat16 vT[2][64 * 40];

    const int tid = threadIdx.x;
    const int w = tid >> 6, l = tid & 63;
    const int l15 = l & 15, lq = l >> 4;

    const int half = tid >> 7;        // 0 -> stage k, 1 -> stage v
    const int idx  = tid & 127;
    const int e0 = (idx >> 4) * 8;
    const int sp = idx & 15;

    const size_t rowbase = (size_t)b * 3136 * 2304 + (half ? 1536 : 768) + h * 64 + e0;

    f32x4 acc[4] = {};
    f32x4 accks = {};

    bf16x8 ones;
    #pragma unroll
    for (int i = 0; i < 8; ++i) ones[i] = (short)0x3F80;   // bf16 1.0

    const int s_begin = ck * 224;
    bf16x8 r0 = *(const bf16x8*)(qkv + rowbase + (size_t)(s_begin + 2 * sp) * 2304);
    bf16x8 r1 = *(const bf16x8*)(qkv + rowbase + (size_t)(s_begin + 2 * sp + 1) * 2304);

    for (int i = 0; i < 7; ++i) {
        const int buf = i & 1;
        __hip_bfloat16* Td = half ? vT[buf] : kT[buf];
        #pragma unroll
        for (int q = 0; q < 8; ++q) {
            unsigned pk = ((unsigned)(unsigned short)r0[q]) |
                          (((unsigned)(unsigned short)r1[q]) << 16);
            *(unsigned*)(Td + (e0 + q) * 40 + 2 * sp) = pk;
        }
        __syncthreads();
        if (i < 6) {
            const int s0 = s_begin + (i + 1) * 32;
            r0 = *(const bf16x8*)(qkv + rowbase + (size_t)(s0 + 2 * sp) * 2304);
            r1 = *(const bf16x8*)(qkv + rowbase + (size_t)(s0 + 2 * sp + 1) * 2304);
        }
        bf16x8 a = *(const bf16x8*)(vT[buf] + (w * 16 + l15) * 40 + lq * 8);
        bf16x8 bfr[4];
        #pragma unroll
        for (int j = 0; j < 4; ++j)
            bfr[j] = *(const bf16x8*)(kT[buf] + (j * 16 + l15) * 40 + lq * 8);
        #pragma unroll
        for (int j = 0; j < 4; ++j)
            acc[j] = __builtin_amdgcn_mfma_f32_16x16x32_bf16(a, bfr[j], acc[j], 0, 0, 0);
        accks = __builtin_amdgcn_mfma_f32_16x16x32_bf16(ones, bfr[w], accks, 0, 0, 0);
    }

    float* kvdst = kvg + ((size_t)bh << 12);
    #pragma unroll
    for (int j = 0; j < 4; ++j) {
        const int col = j * 16 + l15;
        #pragma unroll
        for (int r = 0; r < 4; ++r) {
            const int row = w * 16 + lq * 4 + r;
            atomicAdd(kvdst + row * 64 + col, acc[j][r]);
        }
    }
    if (lq == 0)
        atomicAdd(ksumg + (bh << 6) + w * 16 + l15, accks[0]);
}

// att[m, h*64+d] = (q[m,:] @ kv^T[d,:]) * 1/(q[m,:].ksum + eps)
// LDS-free, barrier-free. One wave per (b, head-PAIR, 16-row tile): 4 q loads,
// 16 kv loads, 2 z chains, 16 MFMAs -> 4x the independent work per wave vs R4.
__global__ __launch_bounds__(256)
void attn_mfma3(const __hip_bfloat16* __restrict__ qkv,
                const __hip_bfloat16* __restrict__ kvb,
                const float* __restrict__ ksumg,
                __hip_bfloat16* __restrict__ att)
{
    // blockIdx.x = (b*6 + hp)*49 + g ; wave w handles 16-row tile tau = g*4+w (exact 196)
    const int t = blockIdx.x;
    const int g = t % 49;
    const int bhp = t / 49;
    const int hp = bhp % 6, b = bhp / 6;
    const int tid = threadIdx.x;
    const int w = tid >> 6, l = tid & 63;
    const int l15 = l & 15, lq = l >> 4;

    const int tau = g * 4 + w;
    const size_t m0 = (size_t)b * 3136 + (size_t)tau * 16;
    const int h0 = hp * 2;
    const int bh0 = b * 12 + h0;

    // A-fragments for both heads: q[row=l15][e = seg*32 + lq*8 + j]
    const __hip_bfloat16* qrow = qkv + (m0 + l15) * 2304 + h0 * 64;
    bf16x8 aq[4];
    aq[0] = *(const bf16x8*)(qrow + lq * 8);
    aq[1] = *(const bf16x8*)(qrow + 32 + lq * 8);
    aq[2] = *(const bf16x8*)(qrow + 64 + lq * 8);
    aq[3] = *(const bf16x8*)(qrow + 96 + lq * 8);

    const float* ks = ksumg + (bh0 << 6);
    float kse[4][8];
    #pragma unroll
    for (int s = 0; s < 4; ++s) {
        *(float4*)(kse[s])     = *(const float4*)(ks + s * 32 + lq * 8);
        *(float4*)(kse[s] + 4) = *(const float4*)(ks + s * 32 + lq * 8 + 4);
    }
    float zp0 = 0.0f, zp1 = 0.0f;
    #pragma unroll
    for (int j = 0; j < 8; ++j) {
        zp0 += b2f(aq[0][j]) * kse[0][j] + b2f(aq[1][j]) * kse[1][j];
        zp1 += b2f(aq[2][j]) * kse[2][j] + b2f(aq[3][j]) * kse[3][j];
    }
    zp0 += __shfl_xor(zp0, 16); zp0 += __shfl_xor(zp0, 32);
    zp1 += __shfl_xor(zp1, 16); zp1 += __shfl_xor(zp1, 32);
    const float zr0 = 1.0f / (zp0 + EPS_Z);
    const float zr1 = 1.0f / (zp1 + EPS_Z);

    const __hip_bfloat16* kvh = kvb + ((size_t)bh0 << 12);
    f32x4 acc[2][4] = {};
    #pragma unroll
    for (int hh = 0; hh < 2; ++hh) {
        #pragma unroll
        for (int j = 0; j < 4; ++j) {
            bf16x8 b0 = *(const bf16x8*)(kvh + hh * 4096 + (j * 16 + l15) * 64 + lq * 8);
            bf16x8 b1 = *(const bf16x8*)(kvh + hh * 4096 + (j * 16 + l15) * 64 + 32 + lq * 8);
            acc[hh][j] = __builtin_amdgcn_mfma_f32_16x16x32_bf16(aq[hh * 2], b0, acc[hh][j], 0, 0, 0);
            acc[hh][j] = __builtin_amdgcn_mfma_f32_16x16x32_bf16(aq[hh * 2 + 1], b1, acc[hh][j], 0, 0, 0);
        }
    }

    float zrow0[4], zrow1[4];
    #pragma unroll
    for (int r = 0; r < 4; ++r) {
        zrow0[r] = __shfl(zr0, lq * 4 + r);
        zrow1[r] = __shfl(zr1, lq * 4 + r);
    }

    #pragma unroll
    for (int hh = 0; hh < 2; ++hh) {
        #pragma unroll
        for (int j = 0; j < 4; ++j) {
            const int col = j * 16 + l15;
            #pragma unroll
            for (int r = 0; r < 4; ++r) {
                const int row = lq * 4 + r;
                const float zv = hh ? zrow1[r] : zrow0[r];
                att[(m0 + row) * 768 + (h0 + hh) * 64 + col] =
                    __float2bfloat16(acc[hh][j][r] * zv);
            }
        }
    }
}

extern "C" void kernel_launch(void* const* d_in, const int* in_sizes, int n_in,
                              void* d_out, int out_size, void* d_ws, size_t ws_size,
                              hipStream_t stream)
{
    const float* x      = (const float*)d_in[0];   // [25088, 768]
    const float* W_qkv  = (const float*)d_in[1];   // [2304, 768]
    const float* W_proj = (const float*)d_in[2];   // [768, 768]
    const float* b_proj = (const float*)d_in[3];   // [768]
    float* out = (float*)d_out;

    const int M = 25088, K = 768, N1 = 2304, N2 = 768;

    __hip_bfloat16* qkv = (__hip_bfloat16*)d_ws;            // M*N1
    __hip_bfloat16* xb  = qkv + (size_t)M * N1;             // M*K
    __hip_bfloat16* wqb = xb + (size_t)M * K;               // N1*K
    __hip_bfloat16* wpb = wqb + (size_t)N1 * K;             // N2*K
    float* kvg  = (float*)(wpb + (size_t)N2 * K);           // 96*4096 fp32 (kv^T [bh][d][e])
    float* ksum = kvg + 96 * 4096;                          // 96*64 fp32
    __hip_bfloat16* kvb = (__hip_bfloat16*)(ksum + 96 * 64);// 96*4096 bf16
    __hip_bfloat16* att = xb;                               // alias: M*N2 <= M*K

    hipMemsetAsync(kvg, 0, (size_t)(96 * 4096 + 96 * 64) * sizeof(float), stream);

    cvt_f32_bf16<<<(M * K / 4 + 255) / 256, 256, 0, stream>>>(x, xb, M * K / 4);
    cvt_f32_bf16<<<(N1 * K / 4 + 255) / 256, 256, 0, stream>>>(W_qkv, wqb, N1 * K / 4);
    cvt_f32_bf16<<<(N2 * K / 4 + 255) / 256, 256, 0, stream>>>(W_proj, wpb, N2 * K / 4);

    gemm_bt<1, __hip_bfloat16><<<(M / 128) * (N1 / 128), 256, 0, stream>>>(
        xb, wqb, qkv, nullptr, K, N1, N1 / 128);
    kv_mfma_kernel<<<96 * 14, 256, 0, stream>>>(qkv, kvg, ksum);
    cvt_f32_bf16<<<(96 * 4096 / 4 + 255) / 256, 256, 0, stream>>>(kvg, kvb, 96 * 4096 / 4);
    attn_mfma3<<<96 / 2 * 49, 256, 0, stream>>>(qkv, kvb, ksum, att);
    gemm_bt<2, float><<<(M / 128) * (N2 / 128), 256, 0, stream>>>(
        att, wpb, out, b_proj, K, N2, N2 / 128);
}